// Round 9
// baseline (352.072 us; speedup 1.0000x reference)
//
#include <hip/hip_runtime.h>
#include <math.h>

// ---------------------------------------------------------------------------
// HDRNet, N=4, low 256x256, full 1024x1024. R15: 5-launch pipeline.
//   L1: conv0123_fused T=1 — 1x1 splat cell per block, 1024 blocks x 256 thr
//       (R15 fix: R14's 256 blocks = 1 block/CU left CUs idle between the 4
//       LDS stages -> est ~37us. T=1: 4 blocks/CU, 16 waves/CU, LDS 11.5KB,
//       ~3x halo redundancy (~340M MAC = 4.3us chip floor). Predicted 8-14us.)
//   L2: k5 {l0 || g1 || a0}   (R7 verbatim)
//   L3: k6 {l1 || g2 || a1}   (R7 verbatim)
//   L4: kfc (FC chain + grid fuse, z-innermost)  (R7 verbatim)
//   L5: hdr_out_v3 (76us; VALUBusy~96 but ~10x above instruction-model floor;
//       derived counters are gfx94x-fallback, composition unresolved) (R7 verbatim)
// Evidence trail:
//   R7 352 (8 launches) | R8-R12 barrier line parked (>=50us/sync or died)
//   R13 357 (5 launches, conv fused @1 wave/SIMD) | R14 328.7 (1024 thr)
//   Overhead model: ~100us fixed + ~25-35us per dispatch (fits R7-R14).
// Tile algebra (T=1): splat cell (cy,cx) | t2 3x3 @ (2cy-1,2cx-1) |
// t1 7x7 @ (4cy-3,4cx-3) | t0 15x15 @ (8cy-7,8cx-7) | low rows 16cy-15..+15.
// Local tap index = 2r+k at every level (same recurrence as R13/R14,
// verified passing). OOB entries stored 0; fmaf(w,0,acc)==acc == skip.
// Per-output FMA order identical to R7 kernels -> bit-identical splat.
// Workspace floats: t0 524288 (unused) | t1 262144 (unused) | t2 131072
// (unused) | splat 65536 | l0o 65536 | local 65536 | x1 32768 | x2 16384 |
// avec 1792 | grid 98304
// ---------------------------------------------------------------------------

__device__ __forceinline__ float tanh_fast(float x) {
    float e = __expf(2.0f * x);
    return 1.0f - 2.0f / (e + 1.0f);
}

// ======================= L1: fused conv0..conv3 (T=1) =======================
__global__ __launch_bounds__(256) void conv0123_fused(
    const float* __restrict__ low,
    const float* __restrict__ w0, const float* __restrict__ b0,
    const float* __restrict__ w1, const float* __restrict__ b1,
    const float* __restrict__ w2, const float* __restrict__ b2,
    const float* __restrict__ w3, const float* __restrict__ b3,
    float* __restrict__ splat)
{
    __shared__ float t0s[8 * 225];    // 8 x 15 x 15
    __shared__ float t1s[16 * 49];    // 16 x 7 x 7
    __shared__ float t2s[32 * 9];     // 32 x 3 x 3
    const int tid = (int)threadIdx.x;
    const int n  = blockIdx.x >> 8;
    const int cy = (blockIdx.x >> 4) & 15;
    const int cx = blockIdx.x & 15;
    const int o0h = 8 * cy - 7, o0w = 8 * cx - 7;    // t0 tile origin (128x128)
    const int o1h = 4 * cy - 3, o1w = 4 * cx - 3;    // t1 tile origin (64x64)
    const int o2h = 2 * cy - 1, o2w = 2 * cx - 1;    // t2 tile origin (32x32)

    // ---- conv0: low(3,256,256) -> t0 tile (8,15,15), stride2 pad1 relu ----
    const float* lown = low + (size_t)n * 3 * 65536;
    for (int idx = tid; idx < 8 * 225; idx += 256) {
        int c = idx / 225, p = idx - c * 225;
        int r = p / 15, q = p - r * 15;
        int h0 = o0h + r, w0g = o0w + q;
        float v = 0.0f;
        if ((unsigned)h0 < 128u && (unsigned)w0g < 128u) {
            float acc = b0[c];
            const float* wp = w0 + c * 27;
            int hi0 = h0 * 2 - 1, wi0 = w0g * 2 - 1;
            #pragma unroll
            for (int ci = 0; ci < 3; ++ci) {
                const float* ip = lown + ci * 65536;
                const float* wc = wp + ci * 9;
                #pragma unroll
                for (int kh = 0; kh < 3; ++kh) {
                    int hi = hi0 + kh;
                    if ((unsigned)hi >= 256u) continue;
                    const float* row = ip + hi * 256;
                    #pragma unroll
                    for (int kw = 0; kw < 3; ++kw) {
                        int wi = wi0 + kw;
                        if ((unsigned)wi >= 256u) continue;
                        acc = fmaf(wc[kh * 3 + kw], row[wi], acc);
                    }
                }
            }
            v = fmaxf(acc, 0.0f);
        }
        t0s[idx] = v;
    }
    __syncthreads();

    // ---- conv1: t0 tile -> t1 tile (16,7,7); t0 is 128x128 globally ----
    for (int idx = tid; idx < 16 * 49; idx += 256) {
        int c = idx / 49, p = idx - c * 49;
        int r = p / 7, q = p - r * 7;
        int h1 = o1h + r, w1g = o1w + q;
        float v = 0.0f;
        if ((unsigned)h1 < 64u && (unsigned)w1g < 64u) {
            float acc = b1[c];
            const float* wp = w1 + c * 72;
            #pragma unroll
            for (int ci = 0; ci < 8; ++ci) {
                const float* tc = t0s + ci * 225;
                const float* wc = wp + ci * 9;
                #pragma unroll
                for (int kh = 0; kh < 3; ++kh) {
                    const float* rw = tc + (2 * r + kh) * 15 + 2 * q;
                    acc = fmaf(wc[kh * 3 + 0], rw[0], acc);
                    acc = fmaf(wc[kh * 3 + 1], rw[1], acc);
                    acc = fmaf(wc[kh * 3 + 2], rw[2], acc);
                }
            }
            v = fmaxf(acc, 0.0f);
        }
        t1s[idx] = v;
    }
    __syncthreads();

    // ---- conv2: t1 tile -> t2 tile (32,3,3); t1 is 64x64 globally ----
    // conv_p_dev<16,4> order: 4 partials of 4 ci, left-assoc sum, +b, relu
    for (int idx = tid; idx < 32 * 9; idx += 256) {
        int c = idx / 9, p = idx - c * 9;
        int r = p / 3, q = p - r * 3;
        int h2 = o2h + r, w2g = o2w + q;
        float v = 0.0f;
        if ((unsigned)h2 < 32u && (unsigned)w2g < 32u) {
            const float* wp = w2 + c * 144;
            float ps0 = 0, ps1 = 0, ps2 = 0, ps3 = 0;
            #pragma unroll
            for (int part = 0; part < 4; ++part) {
                float a = 0.0f;
                #pragma unroll
                for (int cc = 0; cc < 4; ++cc) {
                    int ci = part * 4 + cc;
                    const float* tc = t1s + ci * 49;
                    const float* wc = wp + ci * 9;
                    #pragma unroll
                    for (int kh = 0; kh < 3; ++kh) {
                        const float* rw = tc + (2 * r + kh) * 7 + 2 * q;
                        a = fmaf(wc[kh * 3 + 0], rw[0], a);
                        a = fmaf(wc[kh * 3 + 1], rw[1], a);
                        a = fmaf(wc[kh * 3 + 2], rw[2], a);
                    }
                }
                if (part == 0) ps0 = a; else if (part == 1) ps1 = a;
                else if (part == 2) ps2 = a; else ps3 = a;
            }
            float s = ps0; s += ps1; s += ps2; s += ps3;
            s += b2[c];
            v = fmaxf(s, 0.0f);
        }
        t2s[idx] = v;
    }
    __syncthreads();

    // ---- conv3: t2 tile (3x3) -> splat 1x1x64 (one ch per thread, tid<64) --
    // conv_p_dev<32,8> order: 8 partials of 4 ci, left-assoc sum, +b, relu.
    // Output local coords (0,0): taps = t2s[ci][kh*3+kw].
    if (tid < 64) {
        int c = tid;
        const float* wp = w3 + c * 288;
        float parts[8];
        #pragma unroll
        for (int part = 0; part < 8; ++part) {
            float a = 0.0f;
            #pragma unroll
            for (int cc = 0; cc < 4; ++cc) {
                int ci = part * 4 + cc;
                const float* tc = t2s + ci * 9;
                const float* wc = wp + ci * 9;
                #pragma unroll
                for (int kh = 0; kh < 3; ++kh) {
                    const float* rw = tc + kh * 3;
                    a = fmaf(wc[kh * 3 + 0], rw[0], a);
                    a = fmaf(wc[kh * 3 + 1], rw[1], a);
                    a = fmaf(wc[kh * 3 + 2], rw[2], a);
                }
            }
            parts[part] = a;
        }
        float s = parts[0];
        #pragma unroll
        for (int p = 1; p < 8; ++p) s += parts[p];
        s += b3[c];
        splat[(((size_t)(n * 64 + c)) * 16 + cy) * 16 + cx] = fmaxf(s, 0.0f);
    }
}

// ---- PARTS-way input-channel-split 3x3 conv (R7 verbatim) ----
template<int CIN, int PARTS, int STRIDE, bool RELU, bool HASB,
         int COUT, int HIN, int WIN, int HOUT, int WOUT>
__device__ __forceinline__ void conv_p_dev(
    const float* __restrict__ in, const float* __restrict__ w,
    const float* __restrict__ b, float* __restrict__ out,
    int tb, float* red)
{
    constexpr int CPT = CIN / PARTS;
    constexpr int OPB = 256 / PARTS;
    int part = threadIdx.x / OPB;
    int oidx = threadIdx.x % OPB;
    int o = tb * OPB + oidx;
    int wo = o % WOUT; int t = o / WOUT;
    int ho = t % HOUT; t /= HOUT;
    int co = t % COUT; int n = t / COUT;
    int hi0 = ho * STRIDE - 1, wi0 = wo * STRIDE - 1;
    const float* wp = w + ((size_t)co * CIN + part * CPT) * 9;
    const float* ip = in + ((size_t)n * CIN + part * CPT) * HIN * WIN;
    float acc = 0.0f;
    #pragma unroll
    for (int ci = 0; ci < CPT; ++ci) {
        const float* ic = ip + (size_t)ci * HIN * WIN;
        const float* wc = wp + ci * 9;
        #pragma unroll
        for (int kh = 0; kh < 3; ++kh) {
            int hi = hi0 + kh;
            if ((unsigned)hi >= (unsigned)HIN) continue;
            const float* row = ic + hi * WIN;
            #pragma unroll
            for (int kw = 0; kw < 3; ++kw) {
                int wi = wi0 + kw;
                if ((unsigned)wi >= (unsigned)WIN) continue;
                acc = fmaf(wc[kh * 3 + kw], row[wi], acc);
            }
        }
    }
    red[threadIdx.x] = acc;
    __syncthreads();
    if (part == 0) {
        float s = acc;
        #pragma unroll
        for (int p = 1; p < PARTS; ++p) s += red[p * OPB + oidx];
        if (HASB) s += b[co];
        if (RELU) s = fmaxf(s, 0.0f);
        out[o] = s;
    }
}

// ======================= L2: k5 {l0 || g1 || a0} (R7 verbatim) ==============
__global__ __launch_bounds__(256) void k5_l0_g1_means(
    const float* __restrict__ splat,
    const float* __restrict__ wl0, const float* __restrict__ bl0, float* __restrict__ l0o,
    const float* __restrict__ wg1, const float* __restrict__ bg1, float* __restrict__ x1,
    float* __restrict__ avec)
{
    __shared__ float red[256];
    int bid = blockIdx.x;
    if (bid < 4096) {
        conv_p_dev<64, 16, 1, true, true, 64, 16, 16, 16, 16>(splat, wl0, bl0, l0o, bid, red);
    } else if (bid < 6144) {
        conv_p_dev<64, 16, 2, true, true, 128, 16, 16, 8, 8>(splat, wg1, bg1, x1, bid - 4096, red);
    } else {
        int wid = (bid - 6144) * 4 + ((int)threadIdx.x >> 6);   // 0..255
        int lane = threadIdx.x & 63;
        int n = wid >> 6, c = wid & 63;
        const float* p = splat + ((size_t)(n * 64 + c)) * 256;
        float s = p[lane] + p[lane + 64] + p[lane + 128] + p[lane + 192];
        #pragma unroll
        for (int off = 32; off; off >>= 1) s += __shfl_down(s, off, 64);
        if (lane == 0) avec[n * 448 + c] = s * (1.0f / 256.0f);
    }
}

// ======================= L3: k6 {l1 || g2 || a1} (R7 verbatim) ==============
__global__ __launch_bounds__(256) void k6_l1_g2_means(
    const float* __restrict__ l0o, const float* __restrict__ wl1, float* __restrict__ localb,
    const float* __restrict__ x1, const float* __restrict__ wg2,
    const float* __restrict__ bg2, float* __restrict__ x2,
    float* __restrict__ avec)
{
    __shared__ float red[256];
    int bid = blockIdx.x;
    if (bid < 4096) {
        conv_p_dev<64, 16, 1, false, false, 64, 16, 16, 16, 16>(l0o, wl1, nullptr, localb, bid, red);
    } else if (bid < 5120) {
        conv_p_dev<128, 16, 2, true, true, 256, 8, 8, 4, 4>(x1, wg2, bg2, x2, bid - 4096, red);
    } else {
        int wid = (bid - 5120) * 4 + ((int)threadIdx.x >> 6);   // 0..511
        int lane = threadIdx.x & 63;
        int n = wid >> 7, c = wid & 127;
        const float* p = x1 + ((size_t)(n * 128 + c)) * 64;
        float s = p[lane];
        #pragma unroll
        for (int off = 32; off; off >>= 1) s += __shfl_down(s, off, 64);
        if (lane == 0) avec[n * 448 + 64 + c] = s * (1.0f / 64.0f);
    }
}

// ======================= L4: kfc (R7 verbatim, z-innermost grid) ============
__global__ __launch_bounds__(256) void kfc_fuse(
    const float* __restrict__ avec, const float* __restrict__ x2,
    const float* __restrict__ wf1, const float* __restrict__ bf1,
    const float* __restrict__ wf2, const float* __restrict__ bf2,
    const float* __restrict__ wf3, const float* __restrict__ bf3,
    const float* __restrict__ local,
    const float* __restrict__ wlin, const float* __restrict__ blin,
    float* __restrict__ grid)
{
    __shared__ float a[448];
    __shared__ float h1[256];
    __shared__ float h2[128];
    __shared__ float gl[64];
    int n = blockIdx.x / 96; int k = blockIdx.x % 96; int t = threadIdx.x;
    if (t < 192) a[t] = avec[n * 448 + t];
    {
        const float* p = x2 + ((size_t)(n * 256 + t)) * 16;
        float s = 0.0f;
        #pragma unroll
        for (int i = 0; i < 16; ++i) s += p[i];
        a[192 + t] = s * (1.0f / 16.0f);
    }
    __syncthreads();
    {
        float a0 = 0, a1 = 0, a2 = 0, a3 = 0;
        const float* wp = wf1 + (size_t)t * 448;
        for (int i = 0; i < 448; i += 4) {
            a0 = fmaf(wp[i], a[i], a0); a1 = fmaf(wp[i + 1], a[i + 1], a1);
            a2 = fmaf(wp[i + 2], a[i + 2], a2); a3 = fmaf(wp[i + 3], a[i + 3], a3);
        }
        h1[t] = fmaxf(a0 + a1 + a2 + a3 + bf1[t], 0.0f);
    }
    __syncthreads();
    if (t < 128) {
        float a0 = 0, a1 = 0, a2 = 0, a3 = 0;
        const float* wp = wf2 + (size_t)t * 256;
        for (int i = 0; i < 256; i += 4) {
            a0 = fmaf(wp[i], h1[i], a0); a1 = fmaf(wp[i + 1], h1[i + 1], a1);
            a2 = fmaf(wp[i + 2], h1[i + 2], a2); a3 = fmaf(wp[i + 3], h1[i + 3], a3);
        }
        h2[t] = fmaxf(a0 + a1 + a2 + a3 + bf2[t], 0.0f);
    }
    __syncthreads();
    if (t < 64) {
        float a0 = 0, a1 = 0, a2 = 0, a3 = 0;
        const float* wp = wf3 + (size_t)t * 128;
        for (int i = 0; i < 128; i += 4) {
            a0 = fmaf(wp[i], h2[i], a0); a1 = fmaf(wp[i + 1], h2[i + 1], a1);
            a2 = fmaf(wp[i + 2], h2[i + 2], a2); a3 = fmaf(wp[i + 3], h2[i + 3], a3);
        }
        gl[t] = fmaxf(a0 + a1 + a2 + a3 + bf3[t], 0.0f);
    }
    __syncthreads();
    float acc = blin[k];
    const float* wp = wlin + k * 64;
    const float* lo = local + (size_t)n * 64 * 256 + t;
    #pragma unroll 8
    for (int c = 0; c < 64; ++c)
        acc = fmaf(wp[c], fmaxf(gl[c] + lo[c * 256], 0.0f), acc);
    grid[(size_t)n * 24576 + (size_t)t * 96 + (k & 7) * 12 + (k >> 3)] = acc;
}

// ======================= L5: hdr (R7 verbatim) ==============================
__global__ __launch_bounds__(256) void hdr_out_v3(
    const float* __restrict__ full, const float* __restrict__ low,
    const float* __restrict__ grid,
    const float* __restrict__ wgd1, const float* __restrict__ bgd1,
    const float* __restrict__ wgd2, const float* __restrict__ bgd2,
    const float* __restrict__ wau1, const float* __restrict__ bau1,
    const float* __restrict__ wau2, const float* __restrict__ bau2,
    const float* __restrict__ wav1, const float* __restrict__ bav1,
    const float* __restrict__ wav2, const float* __restrict__ bav2,
    float* __restrict__ out)
{
    int tid = blockIdx.x * 256 + threadIdx.x;
    int x = tid & 1023;
    int y = (tid >> 10) & 1023;
    int n = tid >> 20;
    const float* fp = full + ((size_t)n << 20);

    float v[3][3];
    #pragma unroll
    for (int r = 0; r < 3; ++r) {
        int yy = y + r - 1;
        bool okr = (unsigned)yy < 1024u;
        const float* row = fp + (size_t)yy * 1024;
        v[r][0] = (okr && x > 0)    ? row[x - 1] : 0.0f;
        v[r][1] = okr               ? row[x]     : 0.0f;
        v[r][2] = (okr && x < 1023) ? row[x + 1] : 0.0f;
    }

    float gacc = bgd2[0];
    #pragma unroll
    for (int k = 0; k < 16; ++k) {
        const float* wk = wgd1 + k * 9;
        float h = bgd1[k];
        h = fmaf(wk[0], v[0][0], h); h = fmaf(wk[1], v[0][1], h); h = fmaf(wk[2], v[0][2], h);
        h = fmaf(wk[3], v[1][0], h); h = fmaf(wk[4], v[1][1], h); h = fmaf(wk[5], v[1][2], h);
        h = fmaf(wk[6], v[2][0], h); h = fmaf(wk[7], v[2][1], h); h = fmaf(wk[8], v[2][2], h);
        gacc = fmaf(wgd2[k], fmaxf(h, 0.0f), gacc);
    }
    float g = tanh_fast(gacc);

    float gxc = (x * (32.0f / 1023.0f) - 1.0f) * 0.5f;
    float gyc = (y * (32.0f / 1023.0f) - 1.0f) * 0.5f;
    float gzc = 4.0f * g + 3.5f;
    float x0f = floorf(gxc), y0f = floorf(gyc), z0f = floorf(gzc);
    float fx = gxc - x0f, fy = gyc - y0f, fz = gzc - z0f;
    int ix = (int)x0f, iy = (int)y0f, iz = (int)z0f;

    float wx0 = (ix >= 0 && ix < 16) ? (1.0f - fx) : 0.0f;
    float wx1 = (ix + 1 < 16) ? fx : 0.0f;
    float wy0 = (iy >= 0 && iy < 16) ? (1.0f - fy) : 0.0f;
    float wy1 = (iy + 1 < 16) ? fy : 0.0f;
    float wz0 = (iz >= 0 && iz < 8) ? (1.0f - fz) : 0.0f;
    float wz1 = (iz + 1 >= 0 && iz + 1 < 8) ? fz : 0.0f;
    int xi0 = min(max(ix, 0), 15), xi1 = min(ix + 1, 15);
    int yi0 = min(max(iy, 0), 15), yi1 = min(iy + 1, 15);
    int zi0 = min(max(iz, 0), 7),  zi1 = min(max(iz + 1, 0), 7);

    float w00 = wy0 * wx0, w01 = wy0 * wx1, w10 = wy1 * wx0, w11 = wy1 * wx1;

    const float* gb = grid + (size_t)n * 24576;
    const float* c00 = gb + (yi0 * 16 + xi0) * 96;
    const float* c01 = gb + (yi0 * 16 + xi1) * 96;
    const float* c10 = gb + (yi1 * 16 + xi0) * 96;
    const float* c11 = gb + (yi1 * 16 + xi1) * 96;
    int zo0 = zi0 * 12;
    int zo1 = zi1 * 12;

    float acc[12];
    #pragma unroll
    for (int i = 0; i < 12; ++i) acc[i] = 0.0f;

    #define CORNER(PTR, WK) { \
        const float4* q = (const float4*)(PTR); \
        float wk_ = (WK); \
        float4 A = q[0], B = q[1], C = q[2]; \
        acc[0] = fmaf(wk_, A.x, acc[0]); acc[1] = fmaf(wk_, A.y, acc[1]); \
        acc[2] = fmaf(wk_, A.z, acc[2]); acc[3] = fmaf(wk_, A.w, acc[3]); \
        acc[4] = fmaf(wk_, B.x, acc[4]); acc[5] = fmaf(wk_, B.y, acc[5]); \
        acc[6] = fmaf(wk_, B.z, acc[6]); acc[7] = fmaf(wk_, B.w, acc[7]); \
        acc[8] = fmaf(wk_, C.x, acc[8]); acc[9] = fmaf(wk_, C.y, acc[9]); \
        acc[10] = fmaf(wk_, C.z, acc[10]); acc[11] = fmaf(wk_, C.w, acc[11]); }

    CORNER(c00 + zo0, wz0 * w00)
    CORNER(c01 + zo0, wz0 * w01)
    CORNER(c10 + zo0, wz0 * w10)
    CORNER(c11 + zo0, wz0 * w11)
    CORNER(c00 + zo1, wz1 * w00)
    CORNER(c01 + zo1, wz1 * w01)
    CORNER(c10 + zo1, wz1 * w10)
    CORNER(c11 + zo1, wz1 * w11)
    #undef CORNER

    float p = v[1][1];
    float Yv = fmaf(p, acc[3],  acc[0] + acc[1] + acc[2]);
    float U0 = fmaf(p, acc[7],  acc[4] + acc[5] + acc[6]);
    float V0 = fmaf(p, acc[11], acc[8] + acc[9] + acc[10]);

    float uacc = bau2[0];
    #pragma unroll
    for (int k = 0; k < 16; ++k)
        uacc = fmaf(wau2[k], fmaxf(fmaf(wau1[k], U0, bau1[k]), 0.0f), uacc);
    float vacc = bav2[0];
    #pragma unroll
    for (int k = 0; k < 16; ++k)
        vacc = fmaf(wav2[k], fmaxf(fmaf(wav1[k], V0, bav1[k]), 0.0f), vacc);

    float sx = (x + 0.5f) * 0.25f - 0.5f;
    float sy = (y + 0.5f) * 0.25f - 0.5f;
    float sxf = floorf(sx), syf = floorf(sy);
    float fxl = sx - sxf, fyl = sy - syf;
    int jx0 = max((int)sxf, 0), jx1 = min((int)sxf + 1, 255);
    int jy0 = max((int)syf, 0), jy1 = min((int)syf + 1, 255);
    const float* lr1 = low + ((size_t)(n * 3 + 1)) * 65536;
    const float* lr2 = low + ((size_t)(n * 3 + 2)) * 65536;
    float f1 = (1.0f - fyl) * ((1.0f - fxl) * lr1[jy0 * 256 + jx0] + fxl * lr1[jy0 * 256 + jx1])
             + fyl * ((1.0f - fxl) * lr1[jy1 * 256 + jx0] + fxl * lr1[jy1 * 256 + jx1]);
    float f2 = (1.0f - fyl) * ((1.0f - fxl) * lr2[jy0 * 256 + jx0] + fxl * lr2[jy0 * 256 + jx1])
             + fyl * ((1.0f - fxl) * lr2[jy1 * 256 + jx0] + fxl * lr2[jy1 * 256 + jx1]);

    float Uv = tanh_fast(uacc) + f1;
    float Vv = tanh_fast(vacc) + f2;

    size_t base = ((size_t)n * 3) * 1048576 + (size_t)y * 1024 + x;
    out[base]            = Yv;
    out[base + 1048576]  = Uv;
    out[base + 2097152]  = Vv;
}

extern "C" void kernel_launch(void* const* d_in, const int* in_sizes, int n_in,
                              void* d_out, int out_size, void* d_ws, size_t ws_size,
                              hipStream_t stream)
{
    const float* low  = (const float*)d_in[0];
    const float* full = (const float*)d_in[1];
    const float* w0 = (const float*)d_in[2];  const float* b0 = (const float*)d_in[3];
    const float* w1 = (const float*)d_in[4];  const float* b1 = (const float*)d_in[5];
    const float* w2 = (const float*)d_in[6];  const float* b2 = (const float*)d_in[7];
    const float* w3 = (const float*)d_in[8];  const float* b3 = (const float*)d_in[9];
    const float* wl0 = (const float*)d_in[10]; const float* bl0 = (const float*)d_in[11];
    const float* wl1 = (const float*)d_in[12];
    const float* wg1 = (const float*)d_in[13]; const float* bg1 = (const float*)d_in[14];
    const float* wg2 = (const float*)d_in[15]; const float* bg2 = (const float*)d_in[16];
    const float* wf1 = (const float*)d_in[17]; const float* bf1 = (const float*)d_in[18];
    const float* wf2 = (const float*)d_in[19]; const float* bf2 = (const float*)d_in[20];
    const float* wf3 = (const float*)d_in[21]; const float* bf3 = (const float*)d_in[22];
    const float* wlin = (const float*)d_in[23]; const float* blin = (const float*)d_in[24];
    const float* wgd1 = (const float*)d_in[25]; const float* bgd1 = (const float*)d_in[26];
    const float* wgd2 = (const float*)d_in[27]; const float* bgd2 = (const float*)d_in[28];
    const float* wau1 = (const float*)d_in[29]; const float* bau1 = (const float*)d_in[30];
    const float* wau2 = (const float*)d_in[31]; const float* bau2 = (const float*)d_in[32];
    const float* wav1 = (const float*)d_in[33]; const float* bav1 = (const float*)d_in[34];
    const float* wav2 = (const float*)d_in[35]; const float* bav2 = (const float*)d_in[36];
    float* out = (float*)d_out;

    float* ws = (float*)d_ws;
    float* t0b    = ws;                   // unused (kept for layout stability)
    float* t1b    = t0b + 524288;         // unused
    float* t2b    = t1b + 262144;         // unused
    float* splat  = t2b + 131072;
    float* l0o    = splat + 65536;
    float* localb = l0o + 65536;
    float* x1b    = localb + 65536;
    float* x2b    = x1b + 32768;
    float* avec   = x2b + 16384;
    float* gridb  = avec + 1792;
    (void)t0b; (void)t1b;

    conv0123_fused<<<1024, 256, 0, stream>>>(low, w0, b0, w1, b1, w2, b2, w3, b3, splat);
    k5_l0_g1_means<<<6208, 256, 0, stream>>>(splat, wl0, bl0, l0o, wg1, bg1, x1b, avec);
    k6_l1_g2_means<<<5248, 256, 0, stream>>>(l0o, wl1, localb, x1b, wg2, bg2, x2b, avec);
    kfc_fuse<<<384, 256, 0, stream>>>(avec, x2b, wf1, bf1, wf2, bf2, wf3, bf3,
                                      localb, wlin, blin, gridb);
    hdr_out_v3<<<16384, 256, 0, stream>>>(full, low, gridb,
        wgd1, bgd1, wgd2, bgd2, wau1, bau1, wau2, bau2, wav1, bav1, wav2, bav2, out);
}

// Round 10
// 321.488 us; speedup vs baseline: 1.0951x; 1.0951x over previous
//
#include <hip/hip_runtime.h>
#include <math.h>

// ---------------------------------------------------------------------------
// HDRNet, N=4, low 256x256, full 1024x1024. R16: 5-launch pipeline.
//   L1: conv0123_fused v3 — R14 geometry (2x2 cell tile, 256 blocks x 1024
//       thr) + LDS-STAGED low tile (R16 change): lowT[3][47][47]=26KB loaded
//       coalesced, conv0 taps read LDS (stride-2 lanes = 2-way alias, free).
//       R15 showed conv0's scattered global taps are the cost (T=1 raised
//       tap count 2.1x -> +23us). Predicted conv0123 ~35 -> 12-20us.
//   L2: k5 {l0 || g1 || a0}   (R7 verbatim)
//   L3: k6 {l1 || g2 || a1}   (R7 verbatim)
//   L4: kfc (FC chain + grid fuse, z-innermost)  (R7 verbatim)
//   L5: hdr_out_v3 (74-77us, VALU-issue bound)   (R7 verbatim)
// Evidence trail:
//   R7 352 (8 launches) | R8-R12 barrier line parked | R13 357 (conv fused,
//   1 wave/SIMD) | R14 328.7 (1024 thr) | R15 352 (T=1 REGRESSION: halo
//   redundancy on scattered global taps). Non-hdr kernels never in top-5
//   (hdr's 10 iters fill it); conv0123 inferred: R13~64, R14~35, R15~58.
// Tile algebra (2x2): t2 5x5 @ (4ty-1,4tx-1) | t1 11x11 @ (8ty-3,8tx-3) |
// t0 23x23 @ (16ty-7,16tx-7) | low 47x47 @ (32ty-15,32tx-15).
// Local tap = 2r+kh at every level incl. lowT (derived; R13/R14 verified).
// OOB zero-fill == original skip (fmaf(w,0,acc)==acc). Per-output FMA order
// identical to R7 kernels -> bit-identical splat (absmax 0.00390625).
// Workspace floats: t0 524288 (unused) | t1 262144 (unused) | t2 131072
// (unused) | splat 65536 | l0o 65536 | local 65536 | x1 32768 | x2 16384 |
// avec 1792 | grid 98304
// ---------------------------------------------------------------------------

__device__ __forceinline__ float tanh_fast(float x) {
    float e = __expf(2.0f * x);
    return 1.0f - 2.0f / (e + 1.0f);
}

// ======================= L1: fused conv0..conv3 v3 ==========================
__global__ __launch_bounds__(1024) void conv0123_fused(
    const float* __restrict__ low,
    const float* __restrict__ w0, const float* __restrict__ b0,
    const float* __restrict__ w1, const float* __restrict__ b1,
    const float* __restrict__ w2, const float* __restrict__ b2,
    const float* __restrict__ w3, const float* __restrict__ b3,
    float* __restrict__ splat)
{
    __shared__ float lowT[3 * 47 * 47];   // 3 x 47 x 47 = 26.5KB, coalesced fill
    __shared__ float t0s[8 * 529];        // 8 x 23 x 23
    __shared__ float t1s[16 * 121];       // 16 x 11 x 11
    __shared__ float t2s[32 * 25];        // 32 x 5 x 5
    const int tid = (int)threadIdx.x;
    const int n  = blockIdx.x >> 6;
    const int ty = (blockIdx.x >> 3) & 7;
    const int tx = blockIdx.x & 7;
    const int o0h = 16 * ty - 7, o0w = 16 * tx - 7;   // t0 tile origin
    const int o1h = 8 * ty - 3,  o1w = 8 * tx - 3;    // t1 tile origin
    const int o2h = 4 * ty - 1,  o2w = 4 * tx - 1;    // t2 tile origin
    const int lh0 = 32 * ty - 15, lw0 = 32 * tx - 15; // low tile origin

    // ---- stage low tile: 3x47x47, coalesced 47-float rows, zero-fill OOB --
    const float* lown = low + (size_t)n * 3 * 65536;
    for (int idx = tid; idx < 3 * 2209; idx += 1024) {
        int c = idx / 2209, p = idx - c * 2209;
        int r = p / 47, q = p - r * 47;
        int gh = lh0 + r, gw = lw0 + q;
        float v = 0.0f;
        if ((unsigned)gh < 256u && (unsigned)gw < 256u)
            v = lown[c * 65536 + gh * 256 + gw];
        lowT[idx] = v;
    }
    __syncthreads();

    // ---- conv0: lowT -> t0 tile (8,23,23), stride2 pad1 relu (LDS taps) ---
    // global tap (2*(o0h+r)-1+kh, 2*(o0w+q)-1+kw) == lowT[2r+kh][2q+kw]
    for (int idx = tid; idx < 8 * 529; idx += 1024) {
        int c = idx / 529, p = idx - c * 529;
        int r = p / 23, q = p - r * 23;
        int h0 = o0h + r, w0g = o0w + q;
        float v = 0.0f;
        if ((unsigned)h0 < 128u && (unsigned)w0g < 128u) {
            float acc = b0[c];
            const float* wp = w0 + c * 27;
            #pragma unroll
            for (int ci = 0; ci < 3; ++ci) {
                const float* lc = lowT + ci * 2209;
                const float* wc = wp + ci * 9;
                #pragma unroll
                for (int kh = 0; kh < 3; ++kh) {
                    const float* rw = lc + (2 * r + kh) * 47 + 2 * q;
                    acc = fmaf(wc[kh * 3 + 0], rw[0], acc);
                    acc = fmaf(wc[kh * 3 + 1], rw[1], acc);
                    acc = fmaf(wc[kh * 3 + 2], rw[2], acc);
                }
            }
            v = fmaxf(acc, 0.0f);
        }
        t0s[idx] = v;
    }
    __syncthreads();

    // ---- conv1: t0 tile -> t1 tile (16,11,11); t0 is 128x128 globally ----
    for (int idx = tid; idx < 16 * 121; idx += 1024) {
        int c = idx / 121, p = idx - c * 121;
        int r = p / 11, q = p - r * 11;
        int h1 = o1h + r, w1g = o1w + q;
        float v = 0.0f;
        if ((unsigned)h1 < 64u && (unsigned)w1g < 64u) {
            float acc = b1[c];
            const float* wp = w1 + c * 72;
            #pragma unroll
            for (int ci = 0; ci < 8; ++ci) {
                const float* tc = t0s + ci * 529;
                const float* wc = wp + ci * 9;
                #pragma unroll
                for (int kh = 0; kh < 3; ++kh) {
                    const float* rw = tc + (2 * r + kh) * 23 + 2 * q;
                    acc = fmaf(wc[kh * 3 + 0], rw[0], acc);
                    acc = fmaf(wc[kh * 3 + 1], rw[1], acc);
                    acc = fmaf(wc[kh * 3 + 2], rw[2], acc);
                }
            }
            v = fmaxf(acc, 0.0f);
        }
        t1s[idx] = v;
    }
    __syncthreads();

    // ---- conv2: t1 tile -> t2 tile (32,5,5); t1 is 64x64 globally ----
    // conv_p_dev<16,4> order: 4 partials of 4 ci, left-assoc sum, +b, relu
    for (int idx = tid; idx < 32 * 25; idx += 1024) {
        int c = idx / 25, p = idx - c * 25;
        int r = p / 5, q = p - r * 5;
        int h2 = o2h + r, w2g = o2w + q;
        float v = 0.0f;
        if ((unsigned)h2 < 32u && (unsigned)w2g < 32u) {
            const float* wp = w2 + c * 144;
            float ps0 = 0, ps1 = 0, ps2 = 0, ps3 = 0;
            #pragma unroll
            for (int part = 0; part < 4; ++part) {
                float a = 0.0f;
                #pragma unroll
                for (int cc = 0; cc < 4; ++cc) {
                    int ci = part * 4 + cc;
                    const float* tc = t1s + ci * 121;
                    const float* wc = wp + ci * 9;
                    #pragma unroll
                    for (int kh = 0; kh < 3; ++kh) {
                        const float* rw = tc + (2 * r + kh) * 11 + 2 * q;
                        a = fmaf(wc[kh * 3 + 0], rw[0], a);
                        a = fmaf(wc[kh * 3 + 1], rw[1], a);
                        a = fmaf(wc[kh * 3 + 2], rw[2], a);
                    }
                }
                if (part == 0) ps0 = a; else if (part == 1) ps1 = a;
                else if (part == 2) ps2 = a; else ps3 = a;
            }
            float s = ps0; s += ps1; s += ps2; s += ps3;
            s += b2[c];
            v = fmaxf(s, 0.0f);
        }
        t2s[idx] = v;
    }
    __syncthreads();

    // ---- conv3: t2 tile -> splat 2x2x64 (one output per thread, tid<256) --
    // conv_p_dev<32,8> order: 8 partials of 4 ci, left-assoc sum, +b, relu
    if (tid < 256) {
        int c = tid >> 2, sh = (tid >> 1) & 1, sw = tid & 1;
        int ho = 2 * ty + sh, wo = 2 * tx + sw;
        const float* wp = w3 + c * 288;
        float parts[8];
        #pragma unroll
        for (int part = 0; part < 8; ++part) {
            float a = 0.0f;
            #pragma unroll
            for (int cc = 0; cc < 4; ++cc) {
                int ci = part * 4 + cc;
                const float* tc = t2s + ci * 25;
                const float* wc = wp + ci * 9;
                #pragma unroll
                for (int kh = 0; kh < 3; ++kh) {
                    const float* rw = tc + (2 * sh + kh) * 5 + 2 * sw;
                    a = fmaf(wc[kh * 3 + 0], rw[0], a);
                    a = fmaf(wc[kh * 3 + 1], rw[1], a);
                    a = fmaf(wc[kh * 3 + 2], rw[2], a);
                }
            }
            parts[part] = a;
        }
        float s = parts[0];
        #pragma unroll
        for (int p = 1; p < 8; ++p) s += parts[p];
        s += b3[c];
        splat[(((size_t)(n * 64 + c)) * 16 + ho) * 16 + wo] = fmaxf(s, 0.0f);
    }
}

// ---- PARTS-way input-channel-split 3x3 conv (R7 verbatim) ----
template<int CIN, int PARTS, int STRIDE, bool RELU, bool HASB,
         int COUT, int HIN, int WIN, int HOUT, int WOUT>
__device__ __forceinline__ void conv_p_dev(
    const float* __restrict__ in, const float* __restrict__ w,
    const float* __restrict__ b, float* __restrict__ out,
    int tb, float* red)
{
    constexpr int CPT = CIN / PARTS;
    constexpr int OPB = 256 / PARTS;
    int part = threadIdx.x / OPB;
    int oidx = threadIdx.x % OPB;
    int o = tb * OPB + oidx;
    int wo = o % WOUT; int t = o / WOUT;
    int ho = t % HOUT; t /= HOUT;
    int co = t % COUT; int n = t / COUT;
    int hi0 = ho * STRIDE - 1, wi0 = wo * STRIDE - 1;
    const float* wp = w + ((size_t)co * CIN + part * CPT) * 9;
    const float* ip = in + ((size_t)n * CIN + part * CPT) * HIN * WIN;
    float acc = 0.0f;
    #pragma unroll
    for (int ci = 0; ci < CPT; ++ci) {
        const float* ic = ip + (size_t)ci * HIN * WIN;
        const float* wc = wp + ci * 9;
        #pragma unroll
        for (int kh = 0; kh < 3; ++kh) {
            int hi = hi0 + kh;
            if ((unsigned)hi >= (unsigned)HIN) continue;
            const float* row = ic + hi * WIN;
            #pragma unroll
            for (int kw = 0; kw < 3; ++kw) {
                int wi = wi0 + kw;
                if ((unsigned)wi >= (unsigned)WIN) continue;
                acc = fmaf(wc[kh * 3 + kw], row[wi], acc);
            }
        }
    }
    red[threadIdx.x] = acc;
    __syncthreads();
    if (part == 0) {
        float s = acc;
        #pragma unroll
        for (int p = 1; p < PARTS; ++p) s += red[p * OPB + oidx];
        if (HASB) s += b[co];
        if (RELU) s = fmaxf(s, 0.0f);
        out[o] = s;
    }
}

// ======================= L2: k5 {l0 || g1 || a0} (R7 verbatim) ==============
__global__ __launch_bounds__(256) void k5_l0_g1_means(
    const float* __restrict__ splat,
    const float* __restrict__ wl0, const float* __restrict__ bl0, float* __restrict__ l0o,
    const float* __restrict__ wg1, const float* __restrict__ bg1, float* __restrict__ x1,
    float* __restrict__ avec)
{
    __shared__ float red[256];
    int bid = blockIdx.x;
    if (bid < 4096) {
        conv_p_dev<64, 16, 1, true, true, 64, 16, 16, 16, 16>(splat, wl0, bl0, l0o, bid, red);
    } else if (bid < 6144) {
        conv_p_dev<64, 16, 2, true, true, 128, 16, 16, 8, 8>(splat, wg1, bg1, x1, bid - 4096, red);
    } else {
        int wid = (bid - 6144) * 4 + ((int)threadIdx.x >> 6);   // 0..255
        int lane = threadIdx.x & 63;
        int n = wid >> 6, c = wid & 63;
        const float* p = splat + ((size_t)(n * 64 + c)) * 256;
        float s = p[lane] + p[lane + 64] + p[lane + 128] + p[lane + 192];
        #pragma unroll
        for (int off = 32; off; off >>= 1) s += __shfl_down(s, off, 64);
        if (lane == 0) avec[n * 448 + c] = s * (1.0f / 256.0f);
    }
}

// ======================= L3: k6 {l1 || g2 || a1} (R7 verbatim) ==============
__global__ __launch_bounds__(256) void k6_l1_g2_means(
    const float* __restrict__ l0o, const float* __restrict__ wl1, float* __restrict__ localb,
    const float* __restrict__ x1, const float* __restrict__ wg2,
    const float* __restrict__ bg2, float* __restrict__ x2,
    float* __restrict__ avec)
{
    __shared__ float red[256];
    int bid = blockIdx.x;
    if (bid < 4096) {
        conv_p_dev<64, 16, 1, false, false, 64, 16, 16, 16, 16>(l0o, wl1, nullptr, localb, bid, red);
    } else if (bid < 5120) {
        conv_p_dev<128, 16, 2, true, true, 256, 8, 8, 4, 4>(x1, wg2, bg2, x2, bid - 4096, red);
    } else {
        int wid = (bid - 5120) * 4 + ((int)threadIdx.x >> 6);   // 0..511
        int lane = threadIdx.x & 63;
        int n = wid >> 7, c = wid & 127;
        const float* p = x1 + ((size_t)(n * 128 + c)) * 64;
        float s = p[lane];
        #pragma unroll
        for (int off = 32; off; off >>= 1) s += __shfl_down(s, off, 64);
        if (lane == 0) avec[n * 448 + 64 + c] = s * (1.0f / 64.0f);
    }
}

// ======================= L4: kfc (R7 verbatim, z-innermost grid) ============
__global__ __launch_bounds__(256) void kfc_fuse(
    const float* __restrict__ avec, const float* __restrict__ x2,
    const float* __restrict__ wf1, const float* __restrict__ bf1,
    const float* __restrict__ wf2, const float* __restrict__ bf2,
    const float* __restrict__ wf3, const float* __restrict__ bf3,
    const float* __restrict__ local,
    const float* __restrict__ wlin, const float* __restrict__ blin,
    float* __restrict__ grid)
{
    __shared__ float a[448];
    __shared__ float h1[256];
    __shared__ float h2[128];
    __shared__ float gl[64];
    int n = blockIdx.x / 96; int k = blockIdx.x % 96; int t = threadIdx.x;
    if (t < 192) a[t] = avec[n * 448 + t];
    {
        const float* p = x2 + ((size_t)(n * 256 + t)) * 16;
        float s = 0.0f;
        #pragma unroll
        for (int i = 0; i < 16; ++i) s += p[i];
        a[192 + t] = s * (1.0f / 16.0f);
    }
    __syncthreads();
    {
        float a0 = 0, a1 = 0, a2 = 0, a3 = 0;
        const float* wp = wf1 + (size_t)t * 448;
        for (int i = 0; i < 448; i += 4) {
            a0 = fmaf(wp[i], a[i], a0); a1 = fmaf(wp[i + 1], a[i + 1], a1);
            a2 = fmaf(wp[i + 2], a[i + 2], a2); a3 = fmaf(wp[i + 3], a[i + 3], a3);
        }
        h1[t] = fmaxf(a0 + a1 + a2 + a3 + bf1[t], 0.0f);
    }
    __syncthreads();
    if (t < 128) {
        float a0 = 0, a1 = 0, a2 = 0, a3 = 0;
        const float* wp = wf2 + (size_t)t * 256;
        for (int i = 0; i < 256; i += 4) {
            a0 = fmaf(wp[i], h1[i], a0); a1 = fmaf(wp[i + 1], h1[i + 1], a1);
            a2 = fmaf(wp[i + 2], h1[i + 2], a2); a3 = fmaf(wp[i + 3], h1[i + 3], a3);
        }
        h2[t] = fmaxf(a0 + a1 + a2 + a3 + bf2[t], 0.0f);
    }
    __syncthreads();
    if (t < 64) {
        float a0 = 0, a1 = 0, a2 = 0, a3 = 0;
        const float* wp = wf3 + (size_t)t * 128;
        for (int i = 0; i < 128; i += 4) {
            a0 = fmaf(wp[i], h2[i], a0); a1 = fmaf(wp[i + 1], h2[i + 1], a1);
            a2 = fmaf(wp[i + 2], h2[i + 2], a2); a3 = fmaf(wp[i + 3], h2[i + 3], a3);
        }
        gl[t] = fmaxf(a0 + a1 + a2 + a3 + bf3[t], 0.0f);
    }
    __syncthreads();
    float acc = blin[k];
    const float* wp = wlin + k * 64;
    const float* lo = local + (size_t)n * 64 * 256 + t;
    #pragma unroll 8
    for (int c = 0; c < 64; ++c)
        acc = fmaf(wp[c], fmaxf(gl[c] + lo[c * 256], 0.0f), acc);
    grid[(size_t)n * 24576 + (size_t)t * 96 + (k & 7) * 12 + (k >> 3)] = acc;
}

// ======================= L5: hdr (R7 verbatim) ==============================
__global__ __launch_bounds__(256) void hdr_out_v3(
    const float* __restrict__ full, const float* __restrict__ low,
    const float* __restrict__ grid,
    const float* __restrict__ wgd1, const float* __restrict__ bgd1,
    const float* __restrict__ wgd2, const float* __restrict__ bgd2,
    const float* __restrict__ wau1, const float* __restrict__ bau1,
    const float* __restrict__ wau2, const float* __restrict__ bau2,
    const float* __restrict__ wav1, const float* __restrict__ bav1,
    const float* __restrict__ wav2, const float* __restrict__ bav2,
    float* __restrict__ out)
{
    int tid = blockIdx.x * 256 + threadIdx.x;
    int x = tid & 1023;
    int y = (tid >> 10) & 1023;
    int n = tid >> 20;
    const float* fp = full + ((size_t)n << 20);

    float v[3][3];
    #pragma unroll
    for (int r = 0; r < 3; ++r) {
        int yy = y + r - 1;
        bool okr = (unsigned)yy < 1024u;
        const float* row = fp + (size_t)yy * 1024;
        v[r][0] = (okr && x > 0)    ? row[x - 1] : 0.0f;
        v[r][1] = okr               ? row[x]     : 0.0f;
        v[r][2] = (okr && x < 1023) ? row[x + 1] : 0.0f;
    }

    float gacc = bgd2[0];
    #pragma unroll
    for (int k = 0; k < 16; ++k) {
        const float* wk = wgd1 + k * 9;
        float h = bgd1[k];
        h = fmaf(wk[0], v[0][0], h); h = fmaf(wk[1], v[0][1], h); h = fmaf(wk[2], v[0][2], h);
        h = fmaf(wk[3], v[1][0], h); h = fmaf(wk[4], v[1][1], h); h = fmaf(wk[5], v[1][2], h);
        h = fmaf(wk[6], v[2][0], h); h = fmaf(wk[7], v[2][1], h); h = fmaf(wk[8], v[2][2], h);
        gacc = fmaf(wgd2[k], fmaxf(h, 0.0f), gacc);
    }
    float g = tanh_fast(gacc);

    float gxc = (x * (32.0f / 1023.0f) - 1.0f) * 0.5f;
    float gyc = (y * (32.0f / 1023.0f) - 1.0f) * 0.5f;
    float gzc = 4.0f * g + 3.5f;
    float x0f = floorf(gxc), y0f = floorf(gyc), z0f = floorf(gzc);
    float fx = gxc - x0f, fy = gyc - y0f, fz = gzc - z0f;
    int ix = (int)x0f, iy = (int)y0f, iz = (int)z0f;

    float wx0 = (ix >= 0 && ix < 16) ? (1.0f - fx) : 0.0f;
    float wx1 = (ix + 1 < 16) ? fx : 0.0f;
    float wy0 = (iy >= 0 && iy < 16) ? (1.0f - fy) : 0.0f;
    float wy1 = (iy + 1 < 16) ? fy : 0.0f;
    float wz0 = (iz >= 0 && iz < 8) ? (1.0f - fz) : 0.0f;
    float wz1 = (iz + 1 >= 0 && iz + 1 < 8) ? fz : 0.0f;
    int xi0 = min(max(ix, 0), 15), xi1 = min(ix + 1, 15);
    int yi0 = min(max(iy, 0), 15), yi1 = min(iy + 1, 15);
    int zi0 = min(max(iz, 0), 7),  zi1 = min(max(iz + 1, 0), 7);

    float w00 = wy0 * wx0, w01 = wy0 * wx1, w10 = wy1 * wx0, w11 = wy1 * wx1;

    const float* gb = grid + (size_t)n * 24576;
    const float* c00 = gb + (yi0 * 16 + xi0) * 96;
    const float* c01 = gb + (yi0 * 16 + xi1) * 96;
    const float* c10 = gb + (yi1 * 16 + xi0) * 96;
    const float* c11 = gb + (yi1 * 16 + xi1) * 96;
    int zo0 = zi0 * 12;
    int zo1 = zi1 * 12;

    float acc[12];
    #pragma unroll
    for (int i = 0; i < 12; ++i) acc[i] = 0.0f;

    #define CORNER(PTR, WK) { \
        const float4* q = (const float4*)(PTR); \
        float wk_ = (WK); \
        float4 A = q[0], B = q[1], C = q[2]; \
        acc[0] = fmaf(wk_, A.x, acc[0]); acc[1] = fmaf(wk_, A.y, acc[1]); \
        acc[2] = fmaf(wk_, A.z, acc[2]); acc[3] = fmaf(wk_, A.w, acc[3]); \
        acc[4] = fmaf(wk_, B.x, acc[4]); acc[5] = fmaf(wk_, B.y, acc[5]); \
        acc[6] = fmaf(wk_, B.z, acc[6]); acc[7] = fmaf(wk_, B.w, acc[7]); \
        acc[8] = fmaf(wk_, C.x, acc[8]); acc[9] = fmaf(wk_, C.y, acc[9]); \
        acc[10] = fmaf(wk_, C.z, acc[10]); acc[11] = fmaf(wk_, C.w, acc[11]); }

    CORNER(c00 + zo0, wz0 * w00)
    CORNER(c01 + zo0, wz0 * w01)
    CORNER(c10 + zo0, wz0 * w10)
    CORNER(c11 + zo0, wz0 * w11)
    CORNER(c00 + zo1, wz1 * w00)
    CORNER(c01 + zo1, wz1 * w01)
    CORNER(c10 + zo1, wz1 * w10)
    CORNER(c11 + zo1, wz1 * w11)
    #undef CORNER

    float p = v[1][1];
    float Yv = fmaf(p, acc[3],  acc[0] + acc[1] + acc[2]);
    float U0 = fmaf(p, acc[7],  acc[4] + acc[5] + acc[6]);
    float V0 = fmaf(p, acc[11], acc[8] + acc[9] + acc[10]);

    float uacc = bau2[0];
    #pragma unroll
    for (int k = 0; k < 16; ++k)
        uacc = fmaf(wau2[k], fmaxf(fmaf(wau1[k], U0, bau1[k]), 0.0f), uacc);
    float vacc = bav2[0];
    #pragma unroll
    for (int k = 0; k < 16; ++k)
        vacc = fmaf(wav2[k], fmaxf(fmaf(wav1[k], V0, bav1[k]), 0.0f), vacc);

    float sx = (x + 0.5f) * 0.25f - 0.5f;
    float sy = (y + 0.5f) * 0.25f - 0.5f;
    float sxf = floorf(sx), syf = floorf(sy);
    float fxl = sx - sxf, fyl = sy - syf;
    int jx0 = max((int)sxf, 0), jx1 = min((int)sxf + 1, 255);
    int jy0 = max((int)syf, 0), jy1 = min((int)syf + 1, 255);
    const float* lr1 = low + ((size_t)(n * 3 + 1)) * 65536;
    const float* lr2 = low + ((size_t)(n * 3 + 2)) * 65536;
    float f1 = (1.0f - fyl) * ((1.0f - fxl) * lr1[jy0 * 256 + jx0] + fxl * lr1[jy0 * 256 + jx1])
             + fyl * ((1.0f - fxl) * lr1[jy1 * 256 + jx0] + fxl * lr1[jy1 * 256 + jx1]);
    float f2 = (1.0f - fyl) * ((1.0f - fxl) * lr2[jy0 * 256 + jx0] + fxl * lr2[jy0 * 256 + jx1])
             + fyl * ((1.0f - fxl) * lr2[jy1 * 256 + jx0] + fxl * lr2[jy1 * 256 + jx1]);

    float Uv = tanh_fast(uacc) + f1;
    float Vv = tanh_fast(vacc) + f2;

    size_t base = ((size_t)n * 3) * 1048576 + (size_t)y * 1024 + x;
    out[base]            = Yv;
    out[base + 1048576]  = Uv;
    out[base + 2097152]  = Vv;
}

extern "C" void kernel_launch(void* const* d_in, const int* in_sizes, int n_in,
                              void* d_out, int out_size, void* d_ws, size_t ws_size,
                              hipStream_t stream)
{
    const float* low  = (const float*)d_in[0];
    const float* full = (const float*)d_in[1];
    const float* w0 = (const float*)d_in[2];  const float* b0 = (const float*)d_in[3];
    const float* w1 = (const float*)d_in[4];  const float* b1 = (const float*)d_in[5];
    const float* w2 = (const float*)d_in[6];  const float* b2 = (const float*)d_in[7];
    const float* w3 = (const float*)d_in[8];  const float* b3 = (const float*)d_in[9];
    const float* wl0 = (const float*)d_in[10]; const float* bl0 = (const float*)d_in[11];
    const float* wl1 = (const float*)d_in[12];
    const float* wg1 = (const float*)d_in[13]; const float* bg1 = (const float*)d_in[14];
    const float* wg2 = (const float*)d_in[15]; const float* bg2 = (const float*)d_in[16];
    const float* wf1 = (const float*)d_in[17]; const float* bf1 = (const float*)d_in[18];
    const float* wf2 = (const float*)d_in[19]; const float* bf2 = (const float*)d_in[20];
    const float* wf3 = (const float*)d_in[21]; const float* bf3 = (const float*)d_in[22];
    const float* wlin = (const float*)d_in[23]; const float* blin = (const float*)d_in[24];
    const float* wgd1 = (const float*)d_in[25]; const float* bgd1 = (const float*)d_in[26];
    const float* wgd2 = (const float*)d_in[27]; const float* bgd2 = (const float*)d_in[28];
    const float* wau1 = (const float*)d_in[29]; const float* bau1 = (const float*)d_in[30];
    const float* wau2 = (const float*)d_in[31]; const float* bau2 = (const float*)d_in[32];
    const float* wav1 = (const float*)d_in[33]; const float* bav1 = (const float*)d_in[34];
    const float* wav2 = (const float*)d_in[35]; const float* bav2 = (const float*)d_in[36];
    float* out = (float*)d_out;

    float* ws = (float*)d_ws;
    float* t0b    = ws;                   // unused (kept for layout stability)
    float* t1b    = t0b + 524288;         // unused
    float* t2b    = t1b + 262144;         // unused
    float* splat  = t2b + 131072;
    float* l0o    = splat + 65536;
    float* localb = l0o + 65536;
    float* x1b    = localb + 65536;
    float* x2b    = x1b + 32768;
    float* avec   = x2b + 16384;
    float* gridb  = avec + 1792;
    (void)t0b; (void)t1b;

    conv0123_fused<<<256, 1024, 0, stream>>>(low, w0, b0, w1, b1, w2, b2, w3, b3, splat);
    k5_l0_g1_means<<<6208, 256, 0, stream>>>(splat, wl0, bl0, l0o, wg1, bg1, x1b, avec);
    k6_l1_g2_means<<<5248, 256, 0, stream>>>(l0o, wl1, localb, x1b, wg2, bg2, x2b, avec);
    kfc_fuse<<<384, 256, 0, stream>>>(avec, x2b, wf1, bf1, wf2, bf2, wf3, bf3,
                                      localb, wlin, blin, gridb);
    hdr_out_v3<<<16384, 256, 0, stream>>>(full, low, gridb,
        wgd1, bgd1, wgd2, bgd2, wau1, bau1, wau2, bau2, wav1, bav1, wav2, bav2, out);
}